// Round 7
// baseline (353.348 us; speedup 1.0000x reference)
//
#include <hip/hip_runtime.h>
#include <hip/hip_bf16.h>
#include <math.h>

#define BB 4
#define CC 256
#define NN 8192
#define RSM 128
#define RGEO 16

typedef __attribute__((ext_vector_type(8))) short short8v;
typedef __attribute__((ext_vector_type(4))) float f32x4;
typedef __attribute__((ext_vector_type(4))) unsigned int u32x4;

#define MFMA16 __builtin_amdgcn_mfma_f32_16x16x32_bf16

// ---- workspace byte offsets (peak 65.5 MB; ws >= 77.7 MB proven in r1) ----
#define P_QP   0ull          // qp  [B][N][128] bf16   (8 MB)
#define P_KPT  8388608ull    // kp_t[B][128][N] bf16   (8 MB)
#define P_PHIR 16777216ull   // phi_row [B][N][16] bf16 (1 MB)
#define P_PHIT 17825792ull   // phi_t [B][16][N] bf16   (1 MB)
#define P_XT   18874368ull   // x^T bf16 [B][N][256]   (16 MB)
#define P_VT   35651584ull   // v_t [B][256][N] bf16   (16 MB)
#define P_YNT  35651584ull   // y_nt [B][N][256] bf16  (16 MB, overlays v_t after k_kv)
#define P_KVT  52428800ull   // kv_t bf16 [B][256][2048] (4 MB)
#define P_KVF  56623104ull   // kv_f32 [B][256][2048] f32 (8 MB)
#define P_KSUM 65011712ull   // ksum f32 [B][2048] (32 KB)
#define P_DEN  65044480ull   // den [B][N] f32 (128 KB)
#define P_WQK  65175552ull   // Wqk bf16 [128][256]
#define P_WV   65241088ull   // Wv  bf16 [256][256]
#define P_WP   65372160ull   // Wp  bf16 [256][256]
#define P_PSMT 65503232ull   // Psm^T*scale bf16 [64][64]
#define P_BN   65511424ull   // bn f32 [1024]
#define P_H    0ull          // h bf16 [B][256][N] (16 MB, overlays qp+kp_t after k_fsa)

__device__ __forceinline__ unsigned short f2bu(float f){
    __hip_bfloat16 h = __float2bfloat16(f);
    return __builtin_bit_cast(unsigned short, h);
}
__device__ __forceinline__ float bu2f(unsigned short u){
    return __builtin_bit_cast(float, ((unsigned int)u) << 16);
}
__device__ __forceinline__ unsigned int pack2(float a, float b){
    return (unsigned int)f2bu(a) | (((unsigned int)f2bu(b)) << 16);
}
__device__ __forceinline__ int swz128(int row, int cb){ return (row*128 + cb) ^ ((row & 7) << 4); }
__device__ __forceinline__ int swz256(int row, int cb){ return (row*256 + cb) ^ ((row & 7) << 4); }

// bf16-pair product from packed u32 halves: lo = u<<16, hi = u & 0xffff0000
__device__ __forceinline__ unsigned int bmul2(unsigned int uk, unsigned int up, float& ksacc){
    float lo = __builtin_bit_cast(float, uk << 16) * __builtin_bit_cast(float, up << 16);
    float hi = __builtin_bit_cast(float, uk & 0xffff0000u) * __builtin_bit_cast(float, up & 0xffff0000u);
    ksacc += lo + hi;
    return pack2(lo, hi);
}

// stage a 64-row x 64-elem bf16 tile into swizzled LDS (128B rows)
__device__ __forceinline__ void stage64(const unsigned short* __restrict__ g, size_t stride,
                                        char* lds, int t){
    #pragma unroll
    for (int i = 0; i < 2; ++i){
        int id = t + 256*i; int row = id >> 3, q = id & 7;
        short8v v = *(const short8v*)(g + (size_t)row*stride + q*8);
        *(short8v*)(lds + swz128(row, q*16)) = v;
    }
}
__device__ __forceinline__ short8v fld(const char* lds, int row, int cb){
    return *(const short8v*)(lds + swz128(row, cb));
}
// legacy 2x2 step (k_wgemm): 4 waves as 2x2, each wave 32x32
__device__ __forceinline__ void mfma8(const char* As, const char* Bs, f32x4 acc[2][2],
                                      int wm, int wn, int lr, int lq){
    #pragma unroll
    for (int kk = 0; kk < 2; ++kk){
        short8v a0 = fld(As, wm*32 + lr,      kk*64 + lq*16);
        short8v a1 = fld(As, wm*32 + 16 + lr, kk*64 + lq*16);
        short8v b0 = fld(Bs, wn*32 + lr,      kk*64 + lq*16);
        short8v b1 = fld(Bs, wn*32 + 16 + lr, kk*64 + lq*16);
        acc[0][0] = MFMA16(a0, b0, acc[0][0], 0, 0, 0);
        acc[0][1] = MFMA16(a0, b1, acc[0][1], 0, 0, 0);
        acc[1][0] = MFMA16(a1, b0, acc[1][0], 0, 0, 0);
        acc[1][1] = MFMA16(a1, b1, acc[1][1], 0, 0, 0);
    }
}
// 4x4-frag step: wave = 64x64
__device__ __forceinline__ void mfma16s(const char* As, const char* Bs, f32x4 acc[4][4],
                                        int wm, int wn, int lr, int lq){
    #pragma unroll
    for (int kk = 0; kk < 2; ++kk){
        short8v af[4], bf[4];
        #pragma unroll
        for (int f = 0; f < 4; ++f) af[f] = fld(As, wm*64 + f*16 + lr, kk*64 + lq*16);
        #pragma unroll
        for (int f = 0; f < 4; ++f) bf[f] = fld(Bs, wn*64 + f*16 + lr, kk*64 + lq*16);
        #pragma unroll
        for (int fa = 0; fa < 4; ++fa)
            #pragma unroll
            for (int fb = 0; fb < 4; ++fb)
                acc[fa][fb] = MFMA16(af[fa], bf[fb], acc[fa][fb], 0, 0, 0);
    }
}
// 4x2-frag step: wave = 64c x 32n (k_fsa)
__device__ __forceinline__ void mfma4x2(const char* As, const char* Bs, f32x4 acc[4][2],
                                        int wm, int wn, int lr, int lq){
    #pragma unroll
    for (int kk = 0; kk < 2; ++kk){
        short8v af[4], bf[2];
        #pragma unroll
        for (int f = 0; f < 4; ++f) af[f] = fld(As, wm*64 + f*16 + lr, kk*64 + lq*16);
        #pragma unroll
        for (int f = 0; f < 2; ++f) bf[f] = fld(Bs, wn*32 + f*16 + lr, kk*64 + lq*16);
        #pragma unroll
        for (int fa = 0; fa < 4; ++fa)
            #pragma unroll
            for (int fb = 0; fb < 2; ++fb)
                acc[fa][fb] = MFMA16(af[fa], bf[fb], acc[fa][fb], 0, 0, 0);
    }
}

// ---------------------------------------------------------------------------
// prep: bf16 weight conversion
// ---------------------------------------------------------------------------
__global__ __launch_bounds__(256) void k_prep(const float* __restrict__ Wq, const float* __restrict__ Wk,
    const float* __restrict__ Wv, const float* __restrict__ Wp, const float* __restrict__ Psm,
    unsigned short* __restrict__ Wqk_bf, unsigned short* __restrict__ Wv_bf,
    unsigned short* __restrict__ Wp_bf, unsigned short* __restrict__ Psm_t)
{
    const int tid = blockIdx.x*256 + threadIdx.x;
    const int nth = 64*256;
    for (int i = tid; i < 32768; i += nth){
        int o = i >> 8, c = i & 255;
        Wqk_bf[i] = f2bu(o < 64 ? Wq[o*256 + c] : Wk[(o-64)*256 + c]);
    }
    for (int i = tid; i < 65536; i += nth) Wv_bf[i] = f2bu(Wv[i]);
    for (int i = tid; i < 65536; i += nth) Wp_bf[i] = f2bu(Wp[i]);
    for (int i = tid; i < 4096; i += nth){
        int m = i >> 6, o = i & 63;
        Psm_t[i] = f2bu(Psm[o*64 + m] * 0.35355339059327373f);
    }
}

// ---------------------------------------------------------------------------
// x [B][C][N] f32 -> x^T [B][N][C] bf16
// ---------------------------------------------------------------------------
__global__ __launch_bounds__(256) void k_xt(const float* __restrict__ x, unsigned short* __restrict__ xT)
{
    __shared__ float xs[64][65];
    const int t = threadIdx.x;
    const int b  = blockIdx.x >> 9;
    const int ct = (blockIdx.x >> 7) & 3;
    const int nt = blockIdx.x & 127;
    const int c0 = ct*64, n0 = nt*64;
    #pragma unroll
    for (int i = 0; i < 4; ++i){
        int id = t + 256*i; int row = id >> 4, fq = id & 15;
        f32x4 v = *(const f32x4*)(x + ((size_t)(b*CC + c0 + row))*NN + n0 + fq*4);
        xs[row][fq*4+0] = v[0]; xs[row][fq*4+1] = v[1];
        xs[row][fq*4+2] = v[2]; xs[row][fq*4+3] = v[3];
    }
    __syncthreads();
    #pragma unroll
    for (int i = 0; i < 2; ++i){
        int id = t + 256*i; int n = id >> 3, q = id & 7;
        u32x4 o;
        #pragma unroll
        for (int j2 = 0; j2 < 4; ++j2)
            o[j2] = pack2(xs[q*8 + j2*2][n], xs[q*8 + j2*2+1][n]);
        *(u32x4*)(void*)(xT + ((size_t)(b*NN + n0 + n))*CC + c0 + q*8) = o;
    }
}

// ---------------------------------------------------------------------------
// weight GEMM: out[b][c][n] = sum_k A[c][k] * B[b][n][k]
// grid = 4 * 4ct * 128nt = 2048
// ---------------------------------------------------------------------------
__global__ __launch_bounds__(256) void k_wgemm(const unsigned short* __restrict__ A,
    const unsigned short* __restrict__ Bsrc, unsigned short* __restrict__ out, int orows)
{
    __shared__ __align__(16) char As[8192];
    __shared__ __align__(16) char Bs[8192];
    const int t = threadIdx.x;
    const int l = t & 63, w = t >> 6, wm = w >> 1, wn = w & 1, lr = l & 15, lq = l >> 4;
    const int b  = blockIdx.x >> 9;
    const int ct = (blockIdx.x >> 7) & 3;
    const int nt = blockIdx.x & 127;
    const int c0 = ct*64, n0 = nt*64;

    f32x4 acc[2][2] = {};
    for (int ks = 0; ks < 4; ++ks){
        stage64(A + (size_t)c0*256 + ks*64, 256, As, t);
        stage64(Bsrc + ((size_t)(b*NN + n0))*256 + ks*64, 256, Bs, t);
        __syncthreads();
        mfma8(As, Bs, acc, wm, wn, lr, lq);
        __syncthreads();
    }
    #pragma unroll
    for (int mi = 0; mi < 2; ++mi)
        #pragma unroll
        for (int ni = 0; ni < 2; ++ni)
            #pragma unroll
            for (int r = 0; r < 4; ++r){
                int c = c0 + wm*32 + mi*16 + lq*4 + r;
                int n = n0 + wn*32 + ni*16 + lr;
                out[((size_t)(b*orows + c))*NN + n] = f2bu(acc[mi][ni][r]);
            }
}

// ---------------------------------------------------------------------------
// qk: t = Wqk*x (128xN), proj = Psm_t * t, FAVOR+ features ; grid = 512
// ---------------------------------------------------------------------------
__global__ __launch_bounds__(256) void k_qk(const unsigned short* __restrict__ Wqk,
    const unsigned short* __restrict__ xT, const unsigned short* __restrict__ Psm_t,
    unsigned short* __restrict__ qp, unsigned short* __restrict__ kp_t)
{
    __shared__ __align__(16) char As[16384];
    __shared__ __align__(16) char Bs[8192];
    __shared__ __align__(16) char Ts[16384];
    __shared__ __align__(16) char Ps[8192];
    const int t = threadIdx.x;
    const int l = t & 63, w = t >> 6, wm = w >> 1, wn = w & 1, lr = l & 15, lq = l >> 4;
    const int b  = blockIdx.x >> 7;
    const int nt = blockIdx.x & 127;
    const int n0 = nt*64;

    stage64(Psm_t, 64, Ps, t);

    f32x4 acc[4][2] = {};
    for (int ks = 0; ks < 4; ++ks){
        #pragma unroll
        for (int i = 0; i < 4; ++i){
            int id = t + 256*i; int row = id >> 3, q = id & 7;
            short8v v = *(const short8v*)(Wqk + (size_t)row*256 + ks*64 + q*8);
            *(short8v*)(As + swz128(row, q*16)) = v;
        }
        stage64(xT + ((size_t)(b*NN + n0))*256 + ks*64, 256, Bs, t);
        __syncthreads();
        #pragma unroll
        for (int kk = 0; kk < 2; ++kk){
            short8v b0 = fld(Bs, wn*32 + lr,      kk*64 + lq*16);
            short8v b1 = fld(Bs, wn*32 + 16 + lr, kk*64 + lq*16);
            #pragma unroll
            for (int mi = 0; mi < 4; ++mi){
                short8v a = fld(As, wm*64 + mi*16 + lr, kk*64 + lq*16);
                acc[mi][0] = MFMA16(a, b0, acc[mi][0], 0, 0, 0);
                acc[mi][1] = MFMA16(a, b1, acc[mi][1], 0, 0, 0);
            }
        }
        __syncthreads();
    }
    #pragma unroll
    for (int mi = 0; mi < 4; ++mi)
        #pragma unroll
        for (int ni = 0; ni < 2; ++ni){
            int op = (wm*64 + mi*16 + lq*4)*2;
            int nrow = wn*32 + ni*16 + lr;
            *(unsigned int*)(Ts + swz256(nrow, op))     = pack2(acc[mi][ni][0], acc[mi][ni][1]);
            *(unsigned int*)(Ts + swz256(nrow, op + 4)) = pack2(acc[mi][ni][2], acc[mi][ni][3]);
        }
    __syncthreads();

    const float inv128 = 0.08838834764831845f;
    for (int p = 0; p < 2; ++p){
        f32x4 ac[4] = {};
        #pragma unroll
        for (int kk = 0; kk < 2; ++kk){
            short8v bf = *(const short8v*)(Ts + swz256(w*16 + lr, p*128 + kk*64 + lq*16));
            #pragma unroll
            for (int mi = 0; mi < 4; ++mi){
                short8v a = *(const short8v*)(Ps + swz128(mi*16 + lr, kk*64 + lq*16));
                ac[mi] = MFMA16(a, bf, ac[mi], 0, 0, 0);
            }
        }
        float mx = 0.f;
        #pragma unroll
        for (int mi = 0; mi < 4; ++mi)
            #pragma unroll
            for (int r = 0; r < 4; ++r) mx = fmaxf(mx, fabsf(ac[mi][r]));
        mx = fmaxf(mx, __shfl_xor(mx, 16));
        mx = fmaxf(mx, __shfl_xor(mx, 32));
        const int n = n0 + w*16 + lr;
        if (p == 0){
            unsigned short* qr = qp + ((size_t)(b*NN + n))*RSM;
            #pragma unroll
            for (int mi = 0; mi < 4; ++mi){
                float e0 = __expf( ac[mi][0]-mx)*inv128 + 1e-6f;
                float e1 = __expf( ac[mi][1]-mx)*inv128 + 1e-6f;
                float e2 = __expf( ac[mi][2]-mx)*inv128 + 1e-6f;
                float e3 = __expf( ac[mi][3]-mx)*inv128 + 1e-6f;
                float g0 = __expf(-ac[mi][0]-mx)*inv128 + 1e-6f;
                float g1 = __expf(-ac[mi][1]-mx)*inv128 + 1e-6f;
                float g2 = __expf(-ac[mi][2]-mx)*inv128 + 1e-6f;
                float g3 = __expf(-ac[mi][3]-mx)*inv128 + 1e-6f;
                int i0 = mi*16 + lq*4;
                uint2 pu; pu.x = pack2(e0, e1); pu.y = pack2(e2, e3);
                uint2 nu; nu.x = pack2(g0, g1); nu.y = pack2(g2, g3);
                *(uint2*)(void*)(qr + i0)      = pu;
                *(uint2*)(void*)(qr + 64 + i0) = nu;
            }
        } else {
            unsigned short* kb = kp_t + (size_t)(b*RSM)*NN + n;
            #pragma unroll
            for (int mi = 0; mi < 4; ++mi){
                int i0 = mi*16 + lq*4;
                #pragma unroll
                for (int r = 0; r < 4; ++r){
                    kb[(size_t)(i0 + r)*NN]      = f2bu(__expf( ac[mi][r]-mx)*inv128 + 1e-6f);
                    kb[(size_t)(i0 + r + 64)*NN] = f2bu(__expf(-ac[mi][r]-mx)*inv128 + 1e-6f);
                }
            }
        }
    }
}

// ---------------------------------------------------------------------------
// GeoRFF phi ; grid=128
// ---------------------------------------------------------------------------
__global__ __launch_bounds__(256) void k_phi(const float* __restrict__ pos,
    const float* __restrict__ Wg1, const float* __restrict__ bg1,
    const float* __restrict__ Wg2, const float* __restrict__ bg2,
    const float* __restrict__ log_tau, const float* __restrict__ omega,
    unsigned short* __restrict__ phi_row, unsigned short* __restrict__ phi_t)
{
    const int t = threadIdx.x;
    const int b = blockIdx.x >> 5;
    const int n = ((blockIdx.x & 31) << 8) + t;
    const float* pp = pos + ((size_t)(b*NN + n))*3;
    const float p0 = pp[0], p1 = pp[1], p2 = pp[2];
    float hb[16];
    #pragma unroll
    for (int i = 0; i < 16; ++i)
        hb[i] = fmaxf(0.f, fmaf(Wg1[i*3+0], p0, fmaf(Wg1[i*3+1], p1, fmaf(Wg1[i*3+2], p2, bg1[i]))));
    const float tau = log1pf(__expf(log_tau[0])) + 1e-6f;
    const float sc  = sqrtf(2.f*tau);
    float z[16]; float zn = 0.f;
    #pragma unroll
    for (int i = 0; i < 16; ++i){
        float g = bg2[i];
        #pragma unroll
        for (int j = 0; j < 16; ++j) g = fmaf(Wg2[i*16+j], hb[j], g);
        z[i] = sc*g; zn = fmaf(z[i], z[i], zn);
    }
    zn *= 0.5f;
    float val[16];
    #pragma unroll
    for (int m = 0; m < 16; ++m){
        float s = 0.f;
        #pragma unroll
        for (int i = 0; i < 16; ++i) s = fmaf(z[i], omega[i*16+m], s);
        val[m] = __expf(s - zn)*0.25f;
    }
    unsigned short* pr = phi_row + ((size_t)(b*NN + n))*16;
    u32x4 o0, o1;
    #pragma unroll
    for (int j2 = 0; j2 < 4; ++j2){
        o0[j2] = pack2(val[j2*2], val[j2*2+1]);
        o1[j2] = pack2(val[8+j2*2], val[8+j2*2+1]);
    }
    *(u32x4*)(void*)pr = o0;
    *(u32x4*)(void*)(pr + 8) = o1;
    #pragma unroll
    for (int m = 0; m < 16; ++m)
        phi_t[((size_t)(b*RGEO + m))*NN + n] = f2bu(val[m]);
}

// ---------------------------------------------------------------------------
// kv: 128c x 128r tile, 4x4 frags/wave; K-split x16 w/ f32 atomics.
// T14 prefetch: next-iter global loads issued between LDS-write and MFMA.
// ksum = byproduct of Phi build (ct==0 blocks contribute).
// grid = 4b x 16ksl x 2ct x 16rt = 2048
// ---------------------------------------------------------------------------
__global__ __launch_bounds__(256) void k_kv(const unsigned short* __restrict__ kp_t,
    const unsigned short* __restrict__ phi_t, const unsigned short* __restrict__ v_t,
    float* __restrict__ kv_f32, float* __restrict__ ksum)
{
    __shared__ __align__(16) char As[16384];   // v   128c x 64n
    __shared__ __align__(16) char Bs[16384];   // Phi 128r x 64n
    const int t = threadIdx.x;
    const int l = t & 63, w = t >> 6, wm = w >> 1, wn = w & 1, lr = l & 15, lq = l >> 4;
    const int bid = blockIdx.x;
    const int rt  = bid & 15;
    const int ct  = (bid >> 4) & 1;
    const int ksl = (bid >> 5) & 15;
    const int b   = bid >> 9;
    const int c0 = ct*128, r0 = rt*128;

    const int arow = t >> 3, aq = t & 7;            // As: rows arow+32i, bytes aq*16
    const int brow = t >> 1, half = t & 1;          // Bs: row brow, bytes half*64..+63
    const int rg = r0 + brow;
    const unsigned short* kpr = kp_t + ((size_t)(b*RSM  + (rg >> 4)))*NN;
    const unsigned short* phr = phi_t + ((size_t)(b*RGEO + (rg & 15)))*NN;
    const unsigned short* vb  = v_t + ((size_t)(b*CC + c0))*NN;
    float ksacc = 0.f;

    short8v vA[4];
    unsigned int ob[16];
    int nk = ksl*512;

    // prefetch iter 0: 32 elements per thread (full half-row coverage)
    #pragma unroll
    for (int i = 0; i < 4; ++i)
        vA[i] = *(const short8v*)(vb + (size_t)(arow + 32*i)*NN + nk + aq*8);
    #pragma unroll
    for (int g2 = 0; g2 < 4; ++g2){
        u32x4 uk = __builtin_bit_cast(u32x4, *(const short8v*)(kpr + nk + half*32 + g2*8));
        u32x4 up = __builtin_bit_cast(u32x4, *(const short8v*)(phr + nk + half*32 + g2*8));
        #pragma unroll
        for (int j = 0; j < 4; ++j) ob[g2*4 + j] = bmul2(uk[j], up[j], ksacc);
    }

    f32x4 acc[4][4] = {};
    for (int ks = 0; ks < 8; ++ks){
        __syncthreads();                            // prev MFMA done reading LDS
        #pragma unroll
        for (int i = 0; i < 4; ++i)
            *(short8v*)(As + swz128(arow + 32*i, aq*16)) = vA[i];
        #pragma unroll
        for (int g2 = 0; g2 < 4; ++g2){
            u32x4 o; o[0]=ob[g2*4]; o[1]=ob[g2*4+1]; o[2]=ob[g2*4+2]; o[3]=ob[g2*4+3];
            *(u32x4*)(Bs + swz128(brow, half*64 + g2*16)) = o;
        }
        if (ks < 7){                                // issue next-iter loads now
            nk += 64;
            #pragma unroll
            for (int i = 0; i < 4; ++i)
                vA[i] = *(const short8v*)(vb + (size_t)(arow + 32*i)*NN + nk + aq*8);
            #pragma unroll
            for (int g2 = 0; g2 < 4; ++g2){
                u32x4 uk = __builtin_bit_cast(u32x4, *(const short8v*)(kpr + nk + half*32 + g2*8));
                u32x4 up = __builtin_bit_cast(u32x4, *(const short8v*)(phr + nk + half*32 + g2*8));
                #pragma unroll
                for (int j = 0; j < 4; ++j) ob[g2*4 + j] = bmul2(uk[j], up[j], ksacc);
            }
        }
        __syncthreads();
        mfma16s(As, Bs, acc, wm, wn, lr, lq);
    }
    #pragma unroll
    for (int fa = 0; fa < 4; ++fa)
        #pragma unroll
        for (int fb = 0; fb < 4; ++fb)
            #pragma unroll
            for (int e = 0; e < 4; ++e){
                int c = c0 + wm*64 + fa*16 + lq*4 + e;
                int r = r0 + wn*64 + fb*16 + lr;
                atomicAdd(&kv_f32[((size_t)(b*CC + c))*2048 + r], acc[fa][fb][e]);
            }
    if (ct == 0){
        float o = __shfl_xor(ksacc, 1);
        if (half == 0) atomicAdd(&ksum[b*2048 + rg], ksacc + o);
    }
}

// kv_f32 -> kv_t bf16 ; grid = 2048
__global__ __launch_bounds__(256) void k_kvred(const float* __restrict__ kv_f32,
    unsigned short* __restrict__ kv_t)
{
    const size_t i = ((size_t)blockIdx.x*256 + threadIdx.x)*4;
    f32x4 v = *(const f32x4*)(kv_f32 + i);
    uint2 o; o.x = pack2(v[0], v[1]); o.y = pack2(v[2], v[3]);
    *(uint2*)(void*)(kv_t + i) = o;
}

// ---------------------------------------------------------------------------
// den[b][n] = sum_r qp[n][i]*phi[n][j]*ksum[r] + eps ; grid=128
// ---------------------------------------------------------------------------
__global__ __launch_bounds__(256) void k_denom(const unsigned short* __restrict__ qp,
    const unsigned short* __restrict__ phi_row, const float* __restrict__ ksum,
    float* __restrict__ den)
{
    __shared__ float ks[2048];
    const int t = threadIdx.x;
    const int b = blockIdx.x >> 5;
    const int n = ((blockIdx.x & 31) << 8) + t;
    const float* ksrc = ksum + b*2048;
    #pragma unroll
    for (int i = 0; i < 8; ++i){ int idx = t + 256*i; ks[idx] = ksrc[idx]; }
    __syncthreads();
    float phf[16];
    {
        const unsigned short* pr = phi_row + ((size_t)(b*NN + n))*16;
        short8v a = *(const short8v*)pr;
        short8v c = *(const short8v*)(pr + 8);
        #pragma unroll
        for (int j = 0; j < 8; ++j){ phf[j] = bu2f((unsigned short)a[j]); phf[8+j] = bu2f((unsigned short)c[j]); }
    }
    const unsigned short* qr = qp + ((size_t)(b*NN + n))*RSM;
    float acc = 0.f;
    for (int i = 0; i < 128; i += 8){
        short8v qv = *(const short8v*)(qr + i);
        #pragma unroll
        for (int ii = 0; ii < 8; ++ii){
            const float* kk = &ks[(i + ii)*16];
            float s = 0.f;
            #pragma unroll
            for (int j = 0; j < 16; ++j) s = fmaf(phf[j], kk[j], s);
            acc = fmaf(bu2f((unsigned short)qv[ii]), s, acc);
        }
    }
    den[b*NN + n] = acc + 1e-6f;
}

// ---------------------------------------------------------------------------
// fsa: 128c x 64n tile, 4x2 frags/wave; K = r = 2048; T14 prefetch.
// writes y_nt[n][c] = x - fsa/den. grid = 4b x 2ct x 128nt = 1024
// ---------------------------------------------------------------------------
__global__ __launch_bounds__(256) void k_fsa(const unsigned short* __restrict__ kv_t,
    const unsigned short* __restrict__ qp, const unsigned short* __restrict__ phi_row,
    const float* __restrict__ den, const unsigned short* __restrict__ xT,
    unsigned short* __restrict__ y_nt)
{
    __shared__ __align__(16) char Sm[24576];   // As 16K | Bs 8K ; Ys(16K) overlays
    char* As = Sm;
    char* Bs = Sm + 16384;
    const int t = threadIdx.x;
    const int l = t & 63, w = t >> 6, wm = w >> 1, wn = w & 1, lr = l & 15, lq = l >> 4;
    const int nt = blockIdx.x & 127;
    const int ct = (blockIdx.x >> 7) & 1;
    const int b  = blockIdx.x >> 8;
    const int c0 = ct*128, n0 = nt*64;

    const int arow = t >> 3, aq = t & 7;       // As: kv rows arow+32i
    const int brow = t >> 2, quarter = t & 3;  // Bs: n-row brow, r-chunk quarter*16
    float phf[16];
    {
        const unsigned short* pr = phi_row + ((size_t)(b*NN + n0 + brow))*16;
        short8v a = *(const short8v*)pr;
        short8v c = *(const short8v*)(pr + 8);
        #pragma unroll
        for (int j = 0; j < 8; ++j){ phf[j] = bu2f((unsigned short)a[j]); phf[8+j] = bu2f((unsigned short)c[j]); }
    }
    const unsigned short* qrow = qp + ((size_t)(b*NN + n0 + brow))*RSM;
    const unsigned short* kvb  = kv_t + ((size_t)(b*CC + c0))*2048;

    short8v vA[4];
    float qv;
    int rk = 0;
    #pragma unroll
    for (int i = 0; i < 4; ++i)
        vA[i] = *(const short8v*)(kvb + (size_t)(arow + 32*i)*2048 + rk + aq*8);
    qv = bu2f(qrow[(rk >> 4) + quarter]);

    f32x4 acc[4][2] = {};
    for (int ks = 0; ks < 32; ++ks){
        // build this iter's Bs chunk (reg-only)
        u32x4 o0, o1;
        #pragma unroll
        for (int j2 = 0; j2 < 4; ++j2){
            o0[j2] = pack2(qv*phf[j2*2],     qv*phf[j2*2+1]);
            o1[j2] = pack2(qv*phf[8+j2*2],   qv*phf[8+j2*2+1]);
        }
        __syncthreads();                        // prev MFMA done reading LDS
        #pragma unroll
        for (int i = 0; i < 4; ++i)
            *(short8v*)(As + swz128(arow + 32*i, aq*16)) = vA[i];
        *(u32x4*)(Bs + swz128(brow, quarter*32))      = o0;
        *(u32x4*)(Bs + swz128(brow, quarter*32 + 16)) = o1;
        if (ks < 31){                           // issue next-iter loads
            rk += 64;
            #pragma unroll
            for (int i = 0; i < 4; ++i)
                vA[i] = *(const short8v*)(kvb + (size_t)(arow + 32*i)*2048 + rk + aq*8);
            qv = bu2f(qrow[(rk >> 4) + quarter]);
        }
        __syncthreads();
        mfma4x2(As, Bs, acc, wm, wn, lr, lq);
    }
    __syncthreads();                            // all MFMA done before Ys overlay
    // divide + stage to Ys (overlays Sm), rows = n (64 x 256B), cols = c
    float rd[2];
    #pragma unroll
    for (int fb = 0; fb < 2; ++fb)
        rd[fb] = 1.0f / den[(size_t)b*NN + n0 + wn*32 + fb*16 + lr];
    #pragma unroll
    for (int fa = 0; fa < 4; ++fa)
        #pragma unroll
        for (int fb = 0; fb < 2; ++fb){
            int nrow = wn*32 + fb*16 + lr;
            int cb   = (wm*64 + fa*16 + lq*4)*2;
            *(unsigned int*)(Sm + swz256(nrow, cb))     = pack2(acc[fa][fb][0]*rd[fb], acc[fa][fb][1]*rd[fb]);
            *(unsigned int*)(Sm + swz256(nrow, cb + 4)) = pack2(acc[fa][fb][2]*rd[fb], acc[fa][fb][3]*rd[fb]);
        }
    __syncthreads();
    #pragma unroll
    for (int i = 0; i < 4; ++i){
        int id = t + 256*i; int row = id >> 4, q = id & 15;
        short8v fs = *(const short8v*)(Sm + swz256(row, q*16));
        short8v xv = *(const short8v*)(xT + ((size_t)(b*NN + n0 + row))*CC + c0 + q*8);
        u32x4 o;
        #pragma unroll
        for (int j2 = 0; j2 < 4; ++j2){
            float y0 = bu2f((unsigned short)xv[j2*2])   - bu2f((unsigned short)fs[j2*2]);
            float y1 = bu2f((unsigned short)xv[j2*2+1]) - bu2f((unsigned short)fs[j2*2+1]);
            o[j2] = pack2(y0, y1);
        }
        *(u32x4*)(void*)(y_nt + ((size_t)(b*NN + n0 + row))*CC + c0 + q*8) = o;
    }
}

// ---------------------------------------------------------------------------
// BN stats per channel ; grid=256
// ---------------------------------------------------------------------------
__global__ __launch_bounds__(256) void k_bnstat(const unsigned short* __restrict__ h,
    const float* __restrict__ gamma, const float* __restrict__ beta, float* __restrict__ bn)
{
    __shared__ float s1[256], s2[256];
    const int t = threadIdx.x, c = blockIdx.x;
    float a1 = 0.f, a2 = 0.f;
    for (int b = 0; b < 4; ++b){
        const unsigned short* hr = h + ((size_t)(b*CC + c))*NN;
        #pragma unroll
        for (int i = 0; i < 4; ++i){
            short8v v = *(const short8v*)(hr + (t + i*256)*8);
            #pragma unroll
            for (int j = 0; j < 8; ++j){ float f = bu2f((unsigned short)v[j]); a1 += f; a2 = fmaf(f, f, a2); }
        }
    }
    s1[t] = a1; s2[t] = a2; __syncthreads();
    for (int st = 128; st > 0; st >>= 1){
        if (t < st){ s1[t] += s1[t + st]; s2[t] += s2[t + st]; }
        __syncthreads();
    }
    if (t == 0){
        float inv = 1.f/32768.f;
        float mean = s1[0]*inv, var = s2[0]*inv - mean*mean;
        float sc = gamma[c]*rsqrtf(var + 1e-5f);
        bn[512 + c] = sc; bn[768 + c] = fmaf(-mean, sc, beta[c]);
    }
}

// ---------------------------------------------------------------------------
// out = relu(h*s+b) + x ; grid=2048
// ---------------------------------------------------------------------------
__global__ __launch_bounds__(256) void k_apply(const unsigned short* __restrict__ h,
    const float* __restrict__ x, const float* __restrict__ bn, float* __restrict__ out)
{
    const size_t tot8 = (size_t)BB*CC*NN/8;
    for (size_t i = (size_t)blockIdx.x*256 + threadIdx.x; i < tot8; i += 2048*256){
        int c = (int)((i >> 10) & 255);
        float s = bn[512 + c], bb = bn[768 + c];
        short8v hv = *(const short8v*)(h + i*8);
        f32x4 x0 = *(const f32x4*)(x + i*8);
        f32x4 x1 = *(const f32x4*)(x + i*8 + 4);
        f32x4 o0, o1;
        #pragma unroll
        for (int j = 0; j < 4; ++j){
            o0[j] = fmaxf(fmaf(bu2f((unsigned short)hv[j]),     s, bb), 0.f) + x0[j];
            o1[j] = fmaxf(fmaf(bu2f((unsigned short)hv[4 + j]), s, bb), 0.f) + x1[j];
        }
        *(f32x4*)(out + i*8)     = o0;
        *(f32x4*)(out + i*8 + 4) = o1;
    }
}

extern "C" void kernel_launch(void* const* d_in, const int* in_sizes, int n_in,
                              void* d_out, int out_size, void* d_ws, size_t ws_size,
                              hipStream_t stream)
{
    (void)in_sizes; (void)n_in; (void)out_size; (void)ws_size;
    const float* x       = (const float*)d_in[0];
    const float* pos     = (const float*)d_in[1];
    const float* Wq      = (const float*)d_in[2];
    const float* Wk      = (const float*)d_in[3];
    const float* Wv      = (const float*)d_in[4];
    const float* Psm     = (const float*)d_in[5];
    const float* Wg1     = (const float*)d_in[6];
    const float* bg1     = (const float*)d_in[7];
    const float* Wg2     = (const float*)d_in[8];
    const float* bg2     = (const float*)d_in[9];
    const float* log_tau = (const float*)d_in[10];
    const float* omega   = (const float*)d_in[11];
    const float* Wp      = (const float*)d_in[12];
    const float* gamma   = (const float*)d_in[13];
    const float* beta    = (const float*)d_in[14];
    char* W = (char*)d_ws;
    float* out = (float*)d_out;

    unsigned short* qp    = (unsigned short*)(W + P_QP);
    unsigned short* kp_t  = (unsigned short*)(W + P_KPT);
    unsigned short* phir  = (unsigned short*)(W + P_PHIR);
    unsigned short* phit  = (unsigned short*)(W + P_PHIT);
    unsigned short* xT    = (unsigned short*)(W + P_XT);
    unsigned short* v_t   = (unsigned short*)(W + P_VT);
    unsigned short* y_nt  = (unsigned short*)(W + P_YNT);
    unsigned short* kv_t  = (unsigned short*)(W + P_KVT);
    float*          kvf   = (float*)(W + P_KVF);
    float*          ksum  = (float*)(W + P_KSUM);
    float*          den   = (float*)(W + P_DEN);
    unsigned short* Wqk_b = (unsigned short*)(W + P_WQK);
    unsigned short* Wv_b  = (unsigned short*)(W + P_WV);
    unsigned short* Wp_b  = (unsigned short*)(W + P_WP);
    unsigned short* Psm_t = (unsigned short*)(W + P_PSMT);
    float*          bn    = (float*)(W + P_BN);
    unsigned short* hbuf  = (unsigned short*)(W + P_H);

    hipMemsetAsync(W + P_KVF, 0, 8421376, stream);   // kv_f32 + ksum
    k_prep  <<<  64, 256, 0, stream>>>(Wq, Wk, Wv, Wp, Psm, Wqk_b, Wv_b, Wp_b, Psm_t);
    k_xt    <<<2048, 256, 0, stream>>>(x, xT);
    k_wgemm <<<2048, 256, 0, stream>>>(Wv_b, xT, v_t, 256);
    k_qk    <<< 512, 256, 0, stream>>>(Wqk_b, xT, Psm_t, qp, kp_t);
    k_phi   <<< 128, 256, 0, stream>>>(pos, Wg1, bg1, Wg2, bg2, log_tau, omega, phir, phit);
    k_kv    <<<2048, 256, 0, stream>>>(kp_t, phit, v_t, kvf, ksum);
    k_kvred <<<2048, 256, 0, stream>>>(kvf, kv_t);
    k_denom <<< 128, 256, 0, stream>>>(qp, phir, ksum, den);
    k_fsa   <<<1024, 256, 0, stream>>>(kv_t, qp, phir, den, xT, y_nt);
    k_wgemm <<<2048, 256, 0, stream>>>(Wp_b, y_nt, hbuf, 256);
    k_bnstat<<< 256, 256, 0, stream>>>(hbuf, gamma, beta, bn);
    k_apply <<<2048, 256, 0, stream>>>(hbuf, x, bn, out);
}

// Round 8
// 318.104 us; speedup vs baseline: 1.1108x; 1.1108x over previous
//
#include <hip/hip_runtime.h>
#include <hip/hip_bf16.h>
#include <math.h>

#define BB 4
#define CC 256
#define NN 8192
#define RSM 128
#define RGEO 16

typedef __attribute__((ext_vector_type(8))) short short8v;
typedef __attribute__((ext_vector_type(4))) float f32x4;
typedef __attribute__((ext_vector_type(4))) unsigned int u32x4;

#define MFMA16 __builtin_amdgcn_mfma_f32_16x16x32_bf16

// ---- workspace byte offsets (peak 65.5 MB; ws >= 77.7 MB proven in r1) ----
#define P_QP   0ull          // qp  [B][N][128] bf16   (8 MB)
#define P_KPT  8388608ull    // kp_t[B][128][N] bf16   (8 MB)
#define P_PHIR 16777216ull   // phi_row [B][N][16] bf16 (1 MB)
#define P_PHIT 17825792ull   // phi_t [B][16][N] bf16   (1 MB)
#define P_XT   18874368ull   // x^T bf16 [B][N][256]   (16 MB)
#define P_VT   35651584ull   // v_t [B][256][N] bf16   (16 MB)
#define P_YNT  35651584ull   // y_nt [B][N][256] bf16  (16 MB, overlays v_t after k_kv)
#define P_KVT  52428800ull   // kv_t bf16 [B][256][2048] (4 MB)
#define P_KVF  56623104ull   // kv_f32 [B][256][2048] f32 (8 MB)
#define P_KSUM 65011712ull   // ksum f32 [B][2048] (32 KB)
#define P_WQK  65175552ull   // Wqk bf16 [128][256]
#define P_WV   65241088ull   // Wv  bf16 [256][256]
#define P_WP   65372160ull   // Wp  bf16 [256][256]
#define P_PSMT 65503232ull   // Psm^T*scale bf16 [64][64]
#define P_BN   65511424ull   // bn f32 [1024]
#define P_H    0ull          // h bf16 [B][256][N] (16 MB, overlays qp+kp_t after k_fsa)

__device__ __forceinline__ unsigned short f2bu(float f){
    __hip_bfloat16 h = __float2bfloat16(f);
    return __builtin_bit_cast(unsigned short, h);
}
__device__ __forceinline__ float bu2f(unsigned short u){
    return __builtin_bit_cast(float, ((unsigned int)u) << 16);
}
__device__ __forceinline__ unsigned int pack2(float a, float b){
    return (unsigned int)f2bu(a) | (((unsigned int)f2bu(b)) << 16);
}
__device__ __forceinline__ int swz128(int row, int cb){ return (row*128 + cb) ^ ((row & 7) << 4); }
__device__ __forceinline__ int swz256(int row, int cb){ return (row*256 + cb) ^ ((row & 7) << 4); }

// bf16-pair product from packed u32 halves: lo = u<<16, hi = u & 0xffff0000
__device__ __forceinline__ unsigned int bmul2(unsigned int uk, unsigned int up, float& ksacc){
    float lo = __builtin_bit_cast(float, uk << 16) * __builtin_bit_cast(float, up << 16);
    float hi = __builtin_bit_cast(float, uk & 0xffff0000u) * __builtin_bit_cast(float, up & 0xffff0000u);
    ksacc += lo + hi;
    return pack2(lo, hi);
}

// stage a 64-row x 64-elem bf16 tile into swizzled LDS (128B rows)
__device__ __forceinline__ void stage64(const unsigned short* __restrict__ g, size_t stride,
                                        char* lds, int t){
    #pragma unroll
    for (int i = 0; i < 2; ++i){
        int id = t + 256*i; int row = id >> 3, q = id & 7;
        short8v v = *(const short8v*)(g + (size_t)row*stride + q*8);
        *(short8v*)(lds + swz128(row, q*16)) = v;
    }
}
__device__ __forceinline__ short8v fld(const char* lds, int row, int cb){
    return *(const short8v*)(lds + swz128(row, cb));
}
// legacy 2x2 step (k_wgemm): 4 waves as 2x2, each wave 32x32
__device__ __forceinline__ void mfma8(const char* As, const char* Bs, f32x4 acc[2][2],
                                      int wm, int wn, int lr, int lq){
    #pragma unroll
    for (int kk = 0; kk < 2; ++kk){
        short8v a0 = fld(As, wm*32 + lr,      kk*64 + lq*16);
        short8v a1 = fld(As, wm*32 + 16 + lr, kk*64 + lq*16);
        short8v b0 = fld(Bs, wn*32 + lr,      kk*64 + lq*16);
        short8v b1 = fld(Bs, wn*32 + 16 + lr, kk*64 + lq*16);
        acc[0][0] = MFMA16(a0, b0, acc[0][0], 0, 0, 0);
        acc[0][1] = MFMA16(a0, b1, acc[0][1], 0, 0, 0);
        acc[1][0] = MFMA16(a1, b0, acc[1][0], 0, 0, 0);
        acc[1][1] = MFMA16(a1, b1, acc[1][1], 0, 0, 0);
    }
}
// 4x4-frag step: wave = 64x64
__device__ __forceinline__ void mfma16s(const char* As, const char* Bs, f32x4 acc[4][4],
                                        int wm, int wn, int lr, int lq){
    #pragma unroll
    for (int kk = 0; kk < 2; ++kk){
        short8v af[4], bf[4];
        #pragma unroll
        for (int f = 0; f < 4; ++f) af[f] = fld(As, wm*64 + f*16 + lr, kk*64 + lq*16);
        #pragma unroll
        for (int f = 0; f < 4; ++f) bf[f] = fld(Bs, wn*64 + f*16 + lr, kk*64 + lq*16);
        #pragma unroll
        for (int fa = 0; fa < 4; ++fa)
            #pragma unroll
            for (int fb = 0; fb < 4; ++fb)
                acc[fa][fb] = MFMA16(af[fa], bf[fb], acc[fa][fb], 0, 0, 0);
    }
}
// 4x2-frag step: wave = 64c x 32n (k_fsa)
__device__ __forceinline__ void mfma4x2(const char* As, const char* Bs, f32x4 acc[4][2],
                                        int wm, int wn, int lr, int lq){
    #pragma unroll
    for (int kk = 0; kk < 2; ++kk){
        short8v af[4], bf[2];
        #pragma unroll
        for (int f = 0; f < 4; ++f) af[f] = fld(As, wm*64 + f*16 + lr, kk*64 + lq*16);
        #pragma unroll
        for (int f = 0; f < 2; ++f) bf[f] = fld(Bs, wn*32 + f*16 + lr, kk*64 + lq*16);
        #pragma unroll
        for (int fa = 0; fa < 4; ++fa)
            #pragma unroll
            for (int fb = 0; fb < 2; ++fb)
                acc[fa][fb] = MFMA16(af[fa], bf[fb], acc[fa][fb], 0, 0, 0);
    }
}

// ---------------------------------------------------------------------------
// prep: bf16 weight conversion
// ---------------------------------------------------------------------------
__global__ __launch_bounds__(256) void k_prep(const float* __restrict__ Wq, const float* __restrict__ Wk,
    const float* __restrict__ Wv, const float* __restrict__ Wp, const float* __restrict__ Psm,
    unsigned short* __restrict__ Wqk_bf, unsigned short* __restrict__ Wv_bf,
    unsigned short* __restrict__ Wp_bf, unsigned short* __restrict__ Psm_t)
{
    const int tid = blockIdx.x*256 + threadIdx.x;
    const int nth = 64*256;
    for (int i = tid; i < 32768; i += nth){
        int o = i >> 8, c = i & 255;
        Wqk_bf[i] = f2bu(o < 64 ? Wq[o*256 + c] : Wk[(o-64)*256 + c]);
    }
    for (int i = tid; i < 65536; i += nth) Wv_bf[i] = f2bu(Wv[i]);
    for (int i = tid; i < 65536; i += nth) Wp_bf[i] = f2bu(Wp[i]);
    for (int i = tid; i < 4096; i += nth){
        int m = i >> 6, o = i & 63;
        Psm_t[i] = f2bu(Psm[o*64 + m] * 0.35355339059327373f);
    }
}

// ---------------------------------------------------------------------------
// x [B][C][N] f32 -> x^T [B][N][C] bf16
// ---------------------------------------------------------------------------
__global__ __launch_bounds__(256) void k_xt(const float* __restrict__ x, unsigned short* __restrict__ xT)
{
    __shared__ float xs[64][65];
    const int t = threadIdx.x;
    const int b  = blockIdx.x >> 9;
    const int ct = (blockIdx.x >> 7) & 3;
    const int nt = blockIdx.x & 127;
    const int c0 = ct*64, n0 = nt*64;
    #pragma unroll
    for (int i = 0; i < 4; ++i){
        int id = t + 256*i; int row = id >> 4, fq = id & 15;
        f32x4 v = *(const f32x4*)(x + ((size_t)(b*CC + c0 + row))*NN + n0 + fq*4);
        xs[row][fq*4+0] = v[0]; xs[row][fq*4+1] = v[1];
        xs[row][fq*4+2] = v[2]; xs[row][fq*4+3] = v[3];
    }
    __syncthreads();
    #pragma unroll
    for (int i = 0; i < 2; ++i){
        int id = t + 256*i; int n = id >> 3, q = id & 7;
        u32x4 o;
        #pragma unroll
        for (int j2 = 0; j2 < 4; ++j2)
            o[j2] = pack2(xs[q*8 + j2*2][n], xs[q*8 + j2*2+1][n]);
        *(u32x4*)(void*)(xT + ((size_t)(b*NN + n0 + n))*CC + c0 + q*8) = o;
    }
}

// ---------------------------------------------------------------------------
// weight GEMM: out[b][c][n] = sum_k A[c][k] * B[b][n][k]
// grid = 4 * 4ct * 128nt = 2048
// ---------------------------------------------------------------------------
__global__ __launch_bounds__(256) void k_wgemm(const unsigned short* __restrict__ A,
    const unsigned short* __restrict__ Bsrc, unsigned short* __restrict__ out, int orows)
{
    __shared__ __align__(16) char As[8192];
    __shared__ __align__(16) char Bs[8192];
    const int t = threadIdx.x;
    const int l = t & 63, w = t >> 6, wm = w >> 1, wn = w & 1, lr = l & 15, lq = l >> 4;
    const int b  = blockIdx.x >> 9;
    const int ct = (blockIdx.x >> 7) & 3;
    const int nt = blockIdx.x & 127;
    const int c0 = ct*64, n0 = nt*64;

    f32x4 acc[2][2] = {};
    for (int ks = 0; ks < 4; ++ks){
        stage64(A + (size_t)c0*256 + ks*64, 256, As, t);
        stage64(Bsrc + ((size_t)(b*NN + n0))*256 + ks*64, 256, Bs, t);
        __syncthreads();
        mfma8(As, Bs, acc, wm, wn, lr, lq);
        __syncthreads();
    }
    #pragma unroll
    for (int mi = 0; mi < 2; ++mi)
        #pragma unroll
        for (int ni = 0; ni < 2; ++ni)
            #pragma unroll
            for (int r = 0; r < 4; ++r){
                int c = c0 + wm*32 + mi*16 + lq*4 + r;
                int n = n0 + wn*32 + ni*16 + lr;
                out[((size_t)(b*orows + c))*NN + n] = f2bu(acc[mi][ni][r]);
            }
}

// ---------------------------------------------------------------------------
// qk: t = Wqk*x (128xN), proj = Psm_t * t, FAVOR+ features ; grid = 512
// ---------------------------------------------------------------------------
__global__ __launch_bounds__(256) void k_qk(const unsigned short* __restrict__ Wqk,
    const unsigned short* __restrict__ xT, const unsigned short* __restrict__ Psm_t,
    unsigned short* __restrict__ qp, unsigned short* __restrict__ kp_t)
{
    __shared__ __align__(16) char As[16384];
    __shared__ __align__(16) char Bs[8192];
    __shared__ __align__(16) char Ts[16384];
    __shared__ __align__(16) char Ps[8192];
    const int t = threadIdx.x;
    const int l = t & 63, w = t >> 6, wm = w >> 1, wn = w & 1, lr = l & 15, lq = l >> 4;
    const int b  = blockIdx.x >> 7;
    const int nt = blockIdx.x & 127;
    const int n0 = nt*64;

    stage64(Psm_t, 64, Ps, t);

    f32x4 acc[4][2] = {};
    for (int ks = 0; ks < 4; ++ks){
        #pragma unroll
        for (int i = 0; i < 4; ++i){
            int id = t + 256*i; int row = id >> 3, q = id & 7;
            short8v v = *(const short8v*)(Wqk + (size_t)row*256 + ks*64 + q*8);
            *(short8v*)(As + swz128(row, q*16)) = v;
        }
        stage64(xT + ((size_t)(b*NN + n0))*256 + ks*64, 256, Bs, t);
        __syncthreads();
        #pragma unroll
        for (int kk = 0; kk < 2; ++kk){
            short8v b0 = fld(Bs, wn*32 + lr,      kk*64 + lq*16);
            short8v b1 = fld(Bs, wn*32 + 16 + lr, kk*64 + lq*16);
            #pragma unroll
            for (int mi = 0; mi < 4; ++mi){
                short8v a = fld(As, wm*64 + mi*16 + lr, kk*64 + lq*16);
                acc[mi][0] = MFMA16(a, b0, acc[mi][0], 0, 0, 0);
                acc[mi][1] = MFMA16(a, b1, acc[mi][1], 0, 0, 0);
            }
        }
        __syncthreads();
    }
    #pragma unroll
    for (int mi = 0; mi < 4; ++mi)
        #pragma unroll
        for (int ni = 0; ni < 2; ++ni){
            int op = (wm*64 + mi*16 + lq*4)*2;
            int nrow = wn*32 + ni*16 + lr;
            *(unsigned int*)(Ts + swz256(nrow, op))     = pack2(acc[mi][ni][0], acc[mi][ni][1]);
            *(unsigned int*)(Ts + swz256(nrow, op + 4)) = pack2(acc[mi][ni][2], acc[mi][ni][3]);
        }
    __syncthreads();

    const float inv128 = 0.08838834764831845f;
    for (int p = 0; p < 2; ++p){
        f32x4 ac[4] = {};
        #pragma unroll
        for (int kk = 0; kk < 2; ++kk){
            short8v bf = *(const short8v*)(Ts + swz256(w*16 + lr, p*128 + kk*64 + lq*16));
            #pragma unroll
            for (int mi = 0; mi < 4; ++mi){
                short8v a = *(const short8v*)(Ps + swz128(mi*16 + lr, kk*64 + lq*16));
                ac[mi] = MFMA16(a, bf, ac[mi], 0, 0, 0);
            }
        }
        float mx = 0.f;
        #pragma unroll
        for (int mi = 0; mi < 4; ++mi)
            #pragma unroll
            for (int r = 0; r < 4; ++r) mx = fmaxf(mx, fabsf(ac[mi][r]));
        mx = fmaxf(mx, __shfl_xor(mx, 16));
        mx = fmaxf(mx, __shfl_xor(mx, 32));
        const int n = n0 + w*16 + lr;
        if (p == 0){
            unsigned short* qr = qp + ((size_t)(b*NN + n))*RSM;
            #pragma unroll
            for (int mi = 0; mi < 4; ++mi){
                float e0 = __expf( ac[mi][0]-mx)*inv128 + 1e-6f;
                float e1 = __expf( ac[mi][1]-mx)*inv128 + 1e-6f;
                float e2 = __expf( ac[mi][2]-mx)*inv128 + 1e-6f;
                float e3 = __expf( ac[mi][3]-mx)*inv128 + 1e-6f;
                float g0 = __expf(-ac[mi][0]-mx)*inv128 + 1e-6f;
                float g1 = __expf(-ac[mi][1]-mx)*inv128 + 1e-6f;
                float g2 = __expf(-ac[mi][2]-mx)*inv128 + 1e-6f;
                float g3 = __expf(-ac[mi][3]-mx)*inv128 + 1e-6f;
                int i0 = mi*16 + lq*4;
                uint2 pu; pu.x = pack2(e0, e1); pu.y = pack2(e2, e3);
                uint2 nu; nu.x = pack2(g0, g1); nu.y = pack2(g2, g3);
                *(uint2*)(void*)(qr + i0)      = pu;
                *(uint2*)(void*)(qr + 64 + i0) = nu;
            }
        } else {
            unsigned short* kb = kp_t + (size_t)(b*RSM)*NN + n;
            #pragma unroll
            for (int mi = 0; mi < 4; ++mi){
                int i0 = mi*16 + lq*4;
                #pragma unroll
                for (int r = 0; r < 4; ++r){
                    kb[(size_t)(i0 + r)*NN]      = f2bu(__expf( ac[mi][r]-mx)*inv128 + 1e-6f);
                    kb[(size_t)(i0 + r + 64)*NN] = f2bu(__expf(-ac[mi][r]-mx)*inv128 + 1e-6f);
                }
            }
        }
    }
}

// ---------------------------------------------------------------------------
// GeoRFF phi ; grid=128
// ---------------------------------------------------------------------------
__global__ __launch_bounds__(256) void k_phi(const float* __restrict__ pos,
    const float* __restrict__ Wg1, const float* __restrict__ bg1,
    const float* __restrict__ Wg2, const float* __restrict__ bg2,
    const float* __restrict__ log_tau, const float* __restrict__ omega,
    unsigned short* __restrict__ phi_row, unsigned short* __restrict__ phi_t)
{
    const int t = threadIdx.x;
    const int b = blockIdx.x >> 5;
    const int n = ((blockIdx.x & 31) << 8) + t;
    const float* pp = pos + ((size_t)(b*NN + n))*3;
    const float p0 = pp[0], p1 = pp[1], p2 = pp[2];
    float hb[16];
    #pragma unroll
    for (int i = 0; i < 16; ++i)
        hb[i] = fmaxf(0.f, fmaf(Wg1[i*3+0], p0, fmaf(Wg1[i*3+1], p1, fmaf(Wg1[i*3+2], p2, bg1[i]))));
    const float tau = log1pf(__expf(log_tau[0])) + 1e-6f;
    const float sc  = sqrtf(2.f*tau);
    float z[16]; float zn = 0.f;
    #pragma unroll
    for (int i = 0; i < 16; ++i){
        float g = bg2[i];
        #pragma unroll
        for (int j = 0; j < 16; ++j) g = fmaf(Wg2[i*16+j], hb[j], g);
        z[i] = sc*g; zn = fmaf(z[i], z[i], zn);
    }
    zn *= 0.5f;
    float val[16];
    #pragma unroll
    for (int m = 0; m < 16; ++m){
        float s = 0.f;
        #pragma unroll
        for (int i = 0; i < 16; ++i) s = fmaf(z[i], omega[i*16+m], s);
        val[m] = __expf(s - zn)*0.25f;
    }
    unsigned short* pr = phi_row + ((size_t)(b*NN + n))*16;
    u32x4 o0, o1;
    #pragma unroll
    for (int j2 = 0; j2 < 4; ++j2){
        o0[j2] = pack2(val[j2*2], val[j2*2+1]);
        o1[j2] = pack2(val[8+j2*2], val[8+j2*2+1]);
    }
    *(u32x4*)(void*)pr = o0;
    *(u32x4*)(void*)(pr + 8) = o1;
    #pragma unroll
    for (int m = 0; m < 16; ++m)
        phi_t[((size_t)(b*RGEO + m))*NN + n] = f2bu(val[m]);
}

// ---------------------------------------------------------------------------
// kv: 128c x 128r tile, 4x4 frags/wave; K-split x8 w/ f32 atomics.
// T14 prefetch: next-iter global loads issued between LDS-write and MFMA.
// grid = 4b x 8ksl x 2ct x 16rt = 1024
// ---------------------------------------------------------------------------
__global__ __launch_bounds__(256) void k_kv(const unsigned short* __restrict__ kp_t,
    const unsigned short* __restrict__ phi_t, const unsigned short* __restrict__ v_t,
    float* __restrict__ kv_f32, float* __restrict__ ksum)
{
    __shared__ __align__(16) char As[16384];   // v   128c x 64n
    __shared__ __align__(16) char Bs[16384];   // Phi 128r x 64n
    const int t = threadIdx.x;
    const int l = t & 63, w = t >> 6, wm = w >> 1, wn = w & 1, lr = l & 15, lq = l >> 4;
    const int bid = blockIdx.x;
    const int rt  = bid & 15;
    const int ct  = (bid >> 4) & 1;
    const int ksl = (bid >> 5) & 7;
    const int b   = bid >> 8;
    const int c0 = ct*128, r0 = rt*128;

    const int arow = t >> 3, aq = t & 7;            // As: rows arow+32i, bytes aq*16
    const int brow = t >> 1, half = t & 1;          // Bs: row brow, bytes half*64..+63
    const int rg = r0 + brow;
    const unsigned short* kpr = kp_t + ((size_t)(b*RSM  + (rg >> 4)))*NN;
    const unsigned short* phr = phi_t + ((size_t)(b*RGEO + (rg & 15)))*NN;
    const unsigned short* vb  = v_t + ((size_t)(b*CC + c0))*NN;
    float ksacc = 0.f;

    short8v vA[4];
    unsigned int ob[16];
    int nk = ksl*1024;

    // prefetch iter 0: 32 elements per thread (full half-row coverage)
    #pragma unroll
    for (int i = 0; i < 4; ++i)
        vA[i] = *(const short8v*)(vb + (size_t)(arow + 32*i)*NN + nk + aq*8);
    #pragma unroll
    for (int g2 = 0; g2 < 4; ++g2){
        u32x4 uk = __builtin_bit_cast(u32x4, *(const short8v*)(kpr + nk + half*32 + g2*8));
        u32x4 up = __builtin_bit_cast(u32x4, *(const short8v*)(phr + nk + half*32 + g2*8));
        #pragma unroll
        for (int j = 0; j < 4; ++j) ob[g2*4 + j] = bmul2(uk[j], up[j], ksacc);
    }

    f32x4 acc[4][4] = {};
    for (int ks = 0; ks < 16; ++ks){
        __syncthreads();                            // prev MFMA done reading LDS
        #pragma unroll
        for (int i = 0; i < 4; ++i)
            *(short8v*)(As + swz128(arow + 32*i, aq*16)) = vA[i];
        #pragma unroll
        for (int g2 = 0; g2 < 4; ++g2){
            u32x4 o; o[0]=ob[g2*4]; o[1]=ob[g2*4+1]; o[2]=ob[g2*4+2]; o[3]=ob[g2*4+3];
            *(u32x4*)(Bs + swz128(brow, half*64 + g2*16)) = o;
        }
        if (ks < 15){                               // issue next-iter loads now
            nk += 64;
            #pragma unroll
            for (int i = 0; i < 4; ++i)
                vA[i] = *(const short8v*)(vb + (size_t)(arow + 32*i)*NN + nk + aq*8);
            #pragma unroll
            for (int g2 = 0; g2 < 4; ++g2){
                u32x4 uk = __builtin_bit_cast(u32x4, *(const short8v*)(kpr + nk + half*32 + g2*8));
                u32x4 up = __builtin_bit_cast(u32x4, *(const short8v*)(phr + nk + half*32 + g2*8));
                #pragma unroll
                for (int j = 0; j < 4; ++j) ob[g2*4 + j] = bmul2(uk[j], up[j], ksacc);
            }
        }
        __syncthreads();
        mfma16s(As, Bs, acc, wm, wn, lr, lq);
    }
    #pragma unroll
    for (int fa = 0; fa < 4; ++fa)
        #pragma unroll
        for (int fb = 0; fb < 4; ++fb)
            #pragma unroll
            for (int e = 0; e < 4; ++e){
                int c = c0 + wm*64 + fa*16 + lq*4 + e;
                int r = r0 + wn*64 + fb*16 + lr;
                atomicAdd(&kv_f32[((size_t)(b*CC + c))*2048 + r], acc[fa][fb][e]);
            }
    if (ct == 0){
        float o = __shfl_xor(ksacc, 1);
        if (half == 0) atomicAdd(&ksum[b*2048 + rg], ksacc + o);
    }
}

// kv_f32 -> kv_t bf16 ; grid = 2048
__global__ __launch_bounds__(256) void k_kvred(const float* __restrict__ kv_f32,
    unsigned short* __restrict__ kv_t)
{
    const size_t i = ((size_t)blockIdx.x*256 + threadIdx.x)*4;
    f32x4 v = *(const f32x4*)(kv_f32 + i);
    uint2 o; o.x = pack2(v[0], v[1]); o.y = pack2(v[2], v[3]);
    *(uint2*)(void*)(kv_t + i) = o;
}

// ---------------------------------------------------------------------------
// fsa: 128c x 64n tile, 4x2 frags/wave; K = r = 2048; T14 prefetch.
// den computed inline from ksum (LDS) during Phi_q build (k_denom fused).
// writes y_nt[n][c] = x - fsa/den. grid = 4b x 2ct x 128nt = 1024
// ---------------------------------------------------------------------------
__global__ __launch_bounds__(256) void k_fsa(const unsigned short* __restrict__ kv_t,
    const unsigned short* __restrict__ qp, const unsigned short* __restrict__ phi_row,
    const float* __restrict__ ksum, const unsigned short* __restrict__ xT,
    unsigned short* __restrict__ y_nt)
{
    __shared__ __align__(16) char Sm[24576];   // As 16K | Bs 8K ; Ys(16K) overlays
    __shared__ float ksld[2048];               // 8 KB
    __shared__ float denb[64];                 // reciprocal denom per n-row
    char* As = Sm;
    char* Bs = Sm + 16384;
    const int t = threadIdx.x;
    const int l = t & 63, w = t >> 6, wm = w >> 1, wn = w & 1, lr = l & 15, lq = l >> 4;
    const int nt = blockIdx.x & 127;
    const int ct = (blockIdx.x >> 7) & 1;
    const int b  = blockIdx.x >> 8;
    const int c0 = ct*128, n0 = nt*64;

    const int arow = t >> 3, aq = t & 7;       // As: kv rows arow+32i
    const int brow = t >> 2, quarter = t & 3;  // Bs: n-row brow, r-chunk quarter*16
    float phf[16];
    {
        const unsigned short* pr = phi_row + ((size_t)(b*NN + n0 + brow))*16;
        short8v a = *(const short8v*)pr;
        short8v c = *(const short8v*)(pr + 8);
        #pragma unroll
        for (int j = 0; j < 8; ++j){ phf[j] = bu2f((unsigned short)a[j]); phf[8+j] = bu2f((unsigned short)c[j]); }
    }
    const unsigned short* qrow = qp + ((size_t)(b*NN + n0 + brow))*RSM;
    const unsigned short* kvb  = kv_t + ((size_t)(b*CC + c0))*2048;

    #pragma unroll
    for (int i = 0; i < 8; ++i){ int idx = t + 256*i; ksld[idx] = ksum[b*2048 + idx]; }

    short8v vA[4];
    float qv;
    int rk = 0;
    #pragma unroll
    for (int i = 0; i < 4; ++i)
        vA[i] = *(const short8v*)(kvb + (size_t)(arow + 32*i)*2048 + rk + aq*8);
    qv = bu2f(qrow[(rk >> 4) + quarter]);
    __syncthreads();                           // ksld visible

    float den_acc = 0.f;
    f32x4 acc[4][2] = {};
    for (int ks = 0; ks < 32; ++ks){
        // build this iter's Bs chunk (reg-only) + den partial
        float pv[16];
        #pragma unroll
        for (int j = 0; j < 16; ++j) pv[j] = qv*phf[j];
        {
            const float* kr = &ksld[rk + quarter*16];
            f32x4 k0 = *(const f32x4*)(kr);
            f32x4 k1 = *(const f32x4*)(kr + 4);
            f32x4 k2 = *(const f32x4*)(kr + 8);
            f32x4 k3 = *(const f32x4*)(kr + 12);
            #pragma unroll
            for (int j = 0; j < 4; ++j){
                den_acc = fmaf(pv[j],      k0[j], den_acc);
                den_acc = fmaf(pv[4 + j],  k1[j], den_acc);
                den_acc = fmaf(pv[8 + j],  k2[j], den_acc);
                den_acc = fmaf(pv[12 + j], k3[j], den_acc);
            }
        }
        u32x4 o0, o1;
        #pragma unroll
        for (int j2 = 0; j2 < 4; ++j2){
            o0[j2] = pack2(pv[j2*2],     pv[j2*2+1]);
            o1[j2] = pack2(pv[8+j2*2],   pv[8+j2*2+1]);
        }
        __syncthreads();                        // prev MFMA done reading LDS
        #pragma unroll
        for (int i = 0; i < 4; ++i)
            *(short8v*)(As + swz128(arow + 32*i, aq*16)) = vA[i];
        *(u32x4*)(Bs + swz128(brow, quarter*32))      = o0;
        *(u32x4*)(Bs + swz128(brow, quarter*32 + 16)) = o1;
        if (ks < 31){                           // issue next-iter loads
            rk += 64;
            #pragma unroll
            for (int i = 0; i < 4; ++i)
                vA[i] = *(const short8v*)(kvb + (size_t)(arow + 32*i)*2048 + rk + aq*8);
            qv = bu2f(qrow[(rk >> 4) + quarter]);
        }
        __syncthreads();
        mfma4x2(As, Bs, acc, wm, wn, lr, lq);
    }
    // reduce den across the 4 quarter-lanes (lane bits 0-1) -> reciprocal
    den_acc += __shfl_xor(den_acc, 1);
    den_acc += __shfl_xor(den_acc, 2);
    if (quarter == 0) denb[brow] = 1.0f / (den_acc + 1e-6f);
    __syncthreads();                            // all MFMA done + denb visible
    // divide + stage to Ys (overlays Sm), rows = n (64 x 256B), cols = c
    float rd[2];
    #pragma unroll
    for (int fb = 0; fb < 2; ++fb)
        rd[fb] = denb[wn*32 + fb*16 + lr];
    #pragma unroll
    for (int fa = 0; fa < 4; ++fa)
        #pragma unroll
        for (int fb = 0; fb < 2; ++fb){
            int nrow = wn*32 + fb*16 + lr;
            int cb   = (wm*64 + fa*16 + lq*4)*2;
            *(unsigned int*)(Sm + swz256(nrow, cb))     = pack2(acc[fa][fb][0]*rd[fb], acc[fa][fb][1]*rd[fb]);
            *(unsigned int*)(Sm + swz256(nrow, cb + 4)) = pack2(acc[fa][fb][2]*rd[fb], acc[fa][fb][3]*rd[fb]);
        }
    __syncthreads();
    #pragma unroll
    for (int i = 0; i < 4; ++i){
        int id = t + 256*i; int row = id >> 4, q = id & 15;
        short8v fs = *(const short8v*)(Sm + swz256(row, q*16));
        short8v xv = *(const short8v*)(xT + ((size_t)(b*NN + n0 + row))*CC + c0 + q*8);
        u32x4 o;
        #pragma unroll
        for (int j2 = 0; j2 < 4; ++j2){
            float y0 = bu2f((unsigned short)xv[j2*2])   - bu2f((unsigned short)fs[j2*2]);
            float y1 = bu2f((unsigned short)xv[j2*2+1]) - bu2f((unsigned short)fs[j2*2+1]);
            o[j2] = pack2(y0, y1);
        }
        *(u32x4*)(void*)(y_nt + ((size_t)(b*NN + n0 + row))*CC + c0 + q*8) = o;
    }
}

// ---------------------------------------------------------------------------
// BN stats per channel ; grid=256
// ---------------------------------------------------------------------------
__global__ __launch_bounds__(256) void k_bnstat(const unsigned short* __restrict__ h,
    const float* __restrict__ gamma, const float* __restrict__ beta, float* __restrict__ bn)
{
    __shared__ float s1[256], s2[256];
    const int t = threadIdx.x, c = blockIdx.x;
    float a1 = 0.f, a2 = 0.f;
    for (int b = 0; b < 4; ++b){
        const unsigned short* hr = h + ((size_t)(b*CC + c))*NN;
        #pragma unroll
        for (int i = 0; i < 4; ++i){
            short8v v = *(const short8v*)(hr + (t + i*256)*8);
            #pragma unroll
            for (int j = 0; j < 8; ++j){ float f = bu2f((unsigned short)v[j]); a1 += f; a2 = fmaf(f, f, a2); }
        }
    }
    s1[t] = a1; s2[t] = a2; __syncthreads();
    for (int st = 128; st > 0; st >>= 1){
        if (t < st){ s1[t] += s1[t + st]; s2[t] += s2[t + st]; }
        __syncthreads();
    }
    if (t == 0){
        float inv = 1.f/32768.f;
        float mean = s1[0]*inv, var = s2[0]*inv - mean*mean;
        float sc = gamma[c]*rsqrtf(var + 1e-5f);
        bn[512 + c] = sc; bn[768 + c] = fmaf(-mean, sc, beta[c]);
    }
}

// ---------------------------------------------------------------------------
// out = relu(h*s+b) + x ; grid=2048
// ---------------------------------------------------------------------------
__global__ __launch_bounds__(256) void k_apply(const unsigned short* __restrict__ h,
    const float* __restrict__ x, const float* __restrict__ bn, float* __restrict__ out)
{
    const size_t tot8 = (size_t)BB*CC*NN/8;
    for (size_t i = (size_t)blockIdx.x*256 + threadIdx.x; i < tot8; i += 2048*256){
        int c = (int)((i >> 10) & 255);
        float s = bn[512 + c], bb = bn[768 + c];
        short8v hv = *(const short8v*)(h + i*8);
        f32x4 x0 = *(const f32x4*)(x + i*8);
        f32x4 x1 = *(const f32x4*)(x + i*8 + 4);
        f32x4 o0, o1;
        #pragma unroll
        for (int j = 0; j < 4; ++j){
            o0[j] = fmaxf(fmaf(bu2f((unsigned short)hv[j]),     s, bb), 0.f) + x0[j];
            o1[j] = fmaxf(fmaf(bu2f((unsigned short)hv[4 + j]), s, bb), 0.f) + x1[j];
        }
        *(f32x4*)(out + i*8)     = o0;
        *(f32x4*)(out + i*8 + 4) = o1;
    }
}

extern "C" void kernel_launch(void* const* d_in, const int* in_sizes, int n_in,
                              void* d_out, int out_size, void* d_ws, size_t ws_size,
                              hipStream_t stream)
{
    (void)in_sizes; (void)n_in; (void)out_size; (void)ws_size;
    const float* x       = (const float*)d_in[0];
    const float* pos     = (const float*)d_in[1];
    const float* Wq      = (const float*)d_in[2];
    const float* Wk      = (const float*)d_in[3];
    const float* Wv      = (const float*)d_in[4];
    const float* Psm     = (const float*)d_in[5];
    const float* Wg1     = (const float*)d_in[6];
    const float* bg1     = (const float*)d_in[7];
    const float* Wg2     = (const float*)d_in[8];
    const float* bg2     = (const float*)d_in[9];
    const float* log_tau = (const float*)d_in[10];
    const float* omega   = (const float*)d_in[11];
    const float* Wp      = (const float*)d_in[12];
    const float* gamma   = (const float*)d_in[13];
    const float* beta    = (const float*)d_in[14];
    char* W = (char*)d_ws;
    float* out = (float*)d_out;

    unsigned short* qp    = (unsigned short*)(W + P_QP);
    unsigned short* kp_t  = (unsigned short*)(W + P_KPT);
    unsigned short* phir  = (unsigned short*)(W + P_PHIR);
    unsigned short* phit  = (unsigned short*)(W + P_PHIT);
    unsigned short* xT    = (unsigned short*)(W + P_XT);
    unsigned short* v_t   = (unsigned short*)(W + P_VT);
    unsigned short* y_nt  = (unsigned short*)(W + P_YNT);
    unsigned short* kv_t  = (unsigned short*)(W + P_KVT);
    float*          kvf   = (float*)(W + P_KVF);
    float*          ksum  = (float*)(W + P_KSUM);
    unsigned short* Wqk_b = (unsigned short*)(W + P_WQK);
    unsigned short* Wv_b  = (unsigned short*)(W + P_WV);
    unsigned short* Wp_b  = (unsigned short*)(W + P_WP);
    unsigned short* Psm_t = (unsigned short*)(W + P_PSMT);
    float*          bn    = (float*)(W + P_BN);
    unsigned short* hbuf  = (unsigned short*)(W + P_H);

    hipMemsetAsync(W + P_KVF, 0, 8421376, stream);   // kv_f32 + ksum
    k_prep  <<<  64, 256, 0, stream>>>(Wq, Wk, Wv, Wp, Psm, Wqk_b, Wv_b, Wp_b, Psm_t);
    k_xt    <<<2048, 256, 0, stream>>>(x, xT);
    k_wgemm <<<2048, 256, 0, stream>>>(Wv_b, xT, v_t, 256);
    k_qk    <<< 512, 256, 0, stream>>>(Wqk_b, xT, Psm_t, qp, kp_t);
    k_phi   <<< 128, 256, 0, stream>>>(pos, Wg1, bg1, Wg2, bg2, log_tau, omega, phir, phit);
    k_kv    <<<1024, 256, 0, stream>>>(kp_t, phit, v_t, kvf, ksum);
    k_kvred <<<2048, 256, 0, stream>>>(kvf, kv_t);
    k_fsa   <<<1024, 256, 0, stream>>>(kv_t, qp, phir, ksum, xT, y_nt);
    k_wgemm <<<2048, 256, 0, stream>>>(Wp_b, y_nt, hbuf, 256);
    k_bnstat<<< 256, 256, 0, stream>>>(hbuf, gamma, beta, bn);
    k_apply <<<2048, 256, 0, stream>>>(hbuf, x, bn, out);
}